// Round 5
// baseline (243.666 us; speedup 1.0000x reference)
//
#include <hip/hip_runtime.h>

// B=8, F=4, T=S=1024, C=32, C2=64, NH=2, HD=16
// Inputs fp32, output fp32. q/k/v staged as bf16 for MFMA attention.
#define T_LEN 1024

typedef __attribute__((ext_vector_type(8))) short short8;   // 8 bf16 = 4 VGPR (MFMA A/B frag)
typedef __attribute__((ext_vector_type(4))) short short4v;
typedef __attribute__((ext_vector_type(4))) float float4v;  // MFMA C/D frag

__device__ __forceinline__ float gelu_exact(float x) {
    return 0.5f * x * (1.0f + erff(x * 0.70710678118654752440f));
}
__device__ __forceinline__ unsigned short f2bf(float f) {   // round-to-nearest-even
    unsigned u = __float_as_uint(f);
    u += 0x7fffu + ((u >> 16) & 1u);
    return (unsigned short)(u >> 16);
}

// ---------------------------------------------------------------------------
// Merged TCL for q/k/v: one dispatch, 768 blocks.
//   blocks [0,512)   : q from cd  -> qbf  row layout [32][1024][32]
//   blocks [512,640) : k from pkv -> kbf  row layout [8][1024][32]
//   blocks [640,768) : v from pkv -> vtbf transposed [8][2][16][1024]
// conv (causal k=3, 32->64) with sliding-window rows: 18 broadcast b128 LDS
// reads per c-chunk (vs 48 naive), weights lane-resident (96 regs).
// proj (64->32): weight row in 64 regs via b128, activations via b128.
// ---------------------------------------------------------------------------
__global__ __launch_bounds__(256) void tcl_merged(
    const float* __restrict__ cd, const float* __restrict__ pkv,
    const float* __restrict__ wqc, const float* __restrict__ bqc,
    const float* __restrict__ wqp, const float* __restrict__ bqp,
    const float* __restrict__ wkc, const float* __restrict__ bkc,
    const float* __restrict__ wkp, const float* __restrict__ bkp,
    const float* __restrict__ wvc, const float* __restrict__ bvc,
    const float* __restrict__ wvp, const float* __restrict__ bvp,
    unsigned short* __restrict__ qbf, unsigned short* __restrict__ kbf,
    unsigned short* __restrict__ vtbf)
{
    __shared__ float sx[66][32];     // x rows t0-2 .. t0+63 (rows contiguous)
    __shared__ float sh[64][68];     // conv+gelu out, pad 68 (16B-align, bank-safe)
    __shared__ float swp[32][68];    // proj weights [c][o] (row-major, padded)

    const int tid = threadIdx.x;
    const int gb = blockIdx.x;

    const float *src, *wc, *bc, *wp, *bp;
    unsigned short* outb;
    int n, mode;
    if (gb < 512)      { n = gb >> 4;          src = cd;  wc = wqc; bc = bqc; wp = wqp; bp = bqp; outb = qbf;  mode = 0; }
    else if (gb < 640) { n = (gb - 512) >> 4;  src = pkv; wc = wkc; bc = bkc; wp = wkp; bp = bkp; outb = kbf;  mode = 0; }
    else               { n = (gb - 640) >> 4;  src = pkv; wc = wvc; bc = bvc; wp = wvp; bp = bvp; outb = vtbf; mode = 1; }
    const int t0 = (gb & 15) * 64;

    // stage x tile (zero left pad)
    for (int i = tid; i < 66 * 32; i += 256) {
        int r = i >> 5, cc = i & 31;
        int t = t0 - 2 + r;
        sx[r][cc] = (t >= 0) ? src[((size_t)n * T_LEN + t) * 32 + cc] : 0.0f;
    }
    // stage proj weights row-major (coalesced)
    for (int i = tid; i < 2048; i += 256) {
        int cc = i >> 6, oo = i & 63;
        swp[cc][oo] = wp[i];
    }

    const int o = tid & 63;          // conv out channel
    const int tg = tid >> 6;         // wave id -> 16 consecutive t-rows
    float wr[96];
    {
        const float4* w4 = (const float4*)(wc + (size_t)o * 96);
#pragma unroll
        for (int i = 0; i < 24; ++i) {
            float4 u = w4[i];
            wr[i * 4 + 0] = u.x; wr[i * 4 + 1] = u.y;
            wr[i * 4 + 2] = u.z; wr[i * 4 + 3] = u.w;
        }
    }
    const float bco = bc[o];

    __syncthreads();

    // conv + gelu: y[t][o] = b[o] + sum_c sum_tap w[o][c][tap]*x[t-2+tap][c]
    // rows for this wave: rbase..rbase+17 (18 rows for 16 outputs), slid in regs
    float acc[16];
#pragma unroll
    for (int j = 0; j < 16; ++j) acc[j] = bco;
    const int rbase = tg * 16;
#pragma unroll
    for (int c4 = 0; c4 < 8; ++c4) {
        float4 w0 = *(const float4*)&sx[rbase + 0][c4 * 4];
        float4 w1 = *(const float4*)&sx[rbase + 1][c4 * 4];
        const int bi = c4 * 12;      // wr[c*3 + tap], c = c4*4+m
#pragma unroll
        for (int j = 0; j < 16; ++j) {
            float4 x2 = *(const float4*)&sx[rbase + j + 2][c4 * 4];
            acc[j] += wr[bi + 0] * w0.x + wr[bi + 3] * w0.y + wr[bi + 6] * w0.z + wr[bi + 9]  * w0.w
                    + wr[bi + 1] * w1.x + wr[bi + 4] * w1.y + wr[bi + 7] * w1.z + wr[bi + 10] * w1.w
                    + wr[bi + 2] * x2.x + wr[bi + 5] * x2.y + wr[bi + 8] * x2.z + wr[bi + 11] * x2.w;
            w0 = w1; w1 = x2;        // SSA renames after full unroll (no movs)
        }
    }
#pragma unroll
    for (int j = 0; j < 16; ++j) sh[rbase + j][o] = gelu_exact(acc[j]);

    __syncthreads();

    // proj: out[t][c] = bp[c] + sum_o h[t][o]*wp[c][o]
    int cc, rl;
    if (mode == 0) { cc = tid & 31; rl = tid >> 5; }
    else           { cc = tid >> 3; rl = tid & 7; }
    float wcol[64];
#pragma unroll
    for (int k4 = 0; k4 < 16; ++k4) {
        float4 wv = *(const float4*)&swp[cc][k4 * 4];
        wcol[k4 * 4 + 0] = wv.x; wcol[k4 * 4 + 1] = wv.y;
        wcol[k4 * 4 + 2] = wv.z; wcol[k4 * 4 + 3] = wv.w;
    }
    const float bpc = bp[cc];

#pragma unroll 1
    for (int it = 0; it < 8; ++it) {
        int tl = rl + it * 8;
        float a = bpc;
#pragma unroll
        for (int o4 = 0; o4 < 16; ++o4) {
            float4 hv = *(const float4*)&sh[tl][o4 * 4];
            a += wcol[o4 * 4 + 0] * hv.x + wcol[o4 * 4 + 1] * hv.y +
                 wcol[o4 * 4 + 2] * hv.z + wcol[o4 * 4 + 3] * hv.w;
        }
        if (mode == 0) {
            outb[((size_t)n * T_LEN + t0 + tl) * 32 + cc] = f2bf(a);
        } else {
            outb[((size_t)(n * 2 + (cc >> 4)) * 16 + (cc & 15)) * T_LEN + t0 + tl] = f2bf(a);
        }
    }
}

// ---------------------------------------------------------------------------
// MFMA attention. Block = 4 waves; wave = 16 q-rows; grid 64 bfh x 16 t-tiles.
// Per 32-s chunk: 2x QK mfma_f32_16x16x32_bf16 (d zero-padded 16->32),
// exp2 in C-frag, P -> per-wave LDS [t][s] (pitch 36 shorts), read back as
// A-frag (2x ds_read_b64), 1 dense PV MFMA accumulating y.
// Layouts (m89-verified): A[m=ln&15][k=quad*8+j], B[k=quad*8+j][n=ln&15],
// C[row=quad*4+i][col=ln&15].
// ---------------------------------------------------------------------------
__global__ __launch_bounds__(256) void attn_kernel(
    const unsigned short* __restrict__ qbf,   // [32][1024][32] bf16
    const unsigned short* __restrict__ kbf,   // [8][1024][32] bf16
    const unsigned short* __restrict__ vtbf,  // [8*2*16][1024] bf16 (V^T per head)
    float* __restrict__ yws)                  // [32][1024][32] f32
{
    __shared__ unsigned short plds[4 * 16 * 36];

    const int tid = threadIdx.x;
    const int w = tid >> 6;
    const int ln = tid & 63;
    const int sn = ln & 15;
    const int quad = ln >> 4;
    const int g = blockIdx.x;
    const int tt = g & 15;
    const int bfh = g >> 4;
    const int h = bfh & 1;
    const int bf = bfh >> 1;
    const int b = bf >> 2;
    const int trow = tt * 64 + w * 16 + sn;

    short8 aq = {0, 0, 0, 0, 0, 0, 0, 0};
    if (quad < 2)
        aq = *(const short8*)(qbf + ((size_t)bf * T_LEN + trow) * 32 + h * 16 + quad * 8);

    const unsigned short* kb = kbf + (size_t)b * T_LEN * 32 + h * 16 + quad * 8;
    const unsigned short* vb = vtbf + ((size_t)(b * 2 + h) * 16 + sn) * T_LEN + quad * 8;
    unsigned short* pw = plds + w * 576;

    float4v yacc = {0.f, 0.f, 0.f, 0.f};
    float l0 = 0.f, l1 = 0.f, l2 = 0.f, l3 = 0.f;
    const float SC = 0.36067376022224085f;    // 0.25 * log2(e)

#pragma unroll 1
    for (int s0 = 0; s0 < 1024; s0 += 32) {
        short8 bk0 = {0, 0, 0, 0, 0, 0, 0, 0};
        short8 bk1 = {0, 0, 0, 0, 0, 0, 0, 0};
        if (quad < 2) {
            bk0 = *(const short8*)(kb + (size_t)(s0 + sn) * 32);
            bk1 = *(const short8*)(kb + (size_t)(s0 + 16 + sn) * 32);
        }
        float4v z = {0.f, 0.f, 0.f, 0.f};
        float4v c0 = __builtin_amdgcn_mfma_f32_16x16x32_bf16(aq, bk0, z, 0, 0, 0);
        float4v c1 = __builtin_amdgcn_mfma_f32_16x16x32_bf16(aq, bk1, z, 0, 0, 0);

        float p00 = exp2f(c0.x * SC), p01 = exp2f(c0.y * SC);
        float p02 = exp2f(c0.z * SC), p03 = exp2f(c0.w * SC);
        float p10 = exp2f(c1.x * SC), p11 = exp2f(c1.y * SC);
        float p12 = exp2f(c1.z * SC), p13 = exp2f(c1.w * SC);
        l0 += p00 + p10; l1 += p01 + p11;
        l2 += p02 + p12; l3 += p03 + p13;

        const int tb = quad * 4;
        pw[(tb + 0) * 36 + sn]      = f2bf(p00);
        pw[(tb + 1) * 36 + sn]      = f2bf(p01);
        pw[(tb + 2) * 36 + sn]      = f2bf(p02);
        pw[(tb + 3) * 36 + sn]      = f2bf(p03);
        pw[(tb + 0) * 36 + 16 + sn] = f2bf(p10);
        pw[(tb + 1) * 36 + 16 + sn] = f2bf(p11);
        pw[(tb + 2) * 36 + 16 + sn] = f2bf(p12);
        pw[(tb + 3) * 36 + 16 + sn] = f2bf(p13);

        const unsigned short* pr = pw + sn * 36 + quad * 8;
        short4v plo = *(const short4v*)pr;
        short4v phi = *(const short4v*)(pr + 4);
        short8 ap = {plo.x, plo.y, plo.z, plo.w, phi.x, phi.y, phi.z, phi.w};

        short8 bv = *(const short8*)(vb + s0);
        yacc = __builtin_amdgcn_mfma_f32_16x16x32_bf16(ap, bv, yacc, 0, 0, 0);
    }

#pragma unroll
    for (int off = 1; off < 16; off <<= 1) {
        l0 += __shfl_xor(l0, off); l1 += __shfl_xor(l1, off);
        l2 += __shfl_xor(l2, off); l3 += __shfl_xor(l3, off);
    }
    const float i0 = 1.f / l0, i1 = 1.f / l1, i2 = 1.f / l2, i3 = 1.f / l3;

    float* yp = yws + ((size_t)bf * T_LEN + tt * 64 + w * 16 + quad * 4) * 32 + h * 16 + sn;
    yp[0 * 32] = yacc.x * i0;
    yp[1 * 32] = yacc.y * i1;
    yp[2 * 32] = yacc.z * i2;
    yp[3 * 32] = yacc.w * i3;
}

// ---------------------------------------------------------------------------
// Epilogue: out1 = cd + y@Wc^T; h = LN(out1)*ln_w; out = out1 + gelu(h@Wfc^T)@Wmp^T
// ---------------------------------------------------------------------------
__global__ __launch_bounds__(256) void epi_kernel(
    const float* __restrict__ cd, const float* __restrict__ yws,
    const float* __restrict__ wcp, const float* __restrict__ lnw,
    const float* __restrict__ wfc, const float* __restrict__ wmp,
    float* __restrict__ out)
{
    __shared__ float sy[64][32];
    __shared__ float shn[8][36], sg[8][36];
    __shared__ float sln[32];

    const int tid = threadIdx.x;
    const int rl = tid >> 5, c = tid & 31;

    float wa[32], wb[32], wm[32];
#pragma unroll
    for (int j4 = 0; j4 < 8; ++j4) {
        float4 a = *(const float4*)(wcp + c * 32 + j4 * 4);
        wa[j4 * 4 + 0] = a.x; wa[j4 * 4 + 1] = a.y; wa[j4 * 4 + 2] = a.z; wa[j4 * 4 + 3] = a.w;
        float4 f = *(const float4*)(wfc + c * 32 + j4 * 4);
        wb[j4 * 4 + 0] = f.x; wb[j4 * 4 + 1] = f.y; wb[j4 * 4 + 2] = f.z; wb[j4 * 4 + 3] = f.w;
        float4 m = *(const float4*)(wmp + c * 32 + j4 * 4);
        wm[j4 * 4 + 0] = m.x; wm[j4 * 4 + 1] = m.y; wm[j4 * 4 + 2] = m.z; wm[j4 * 4 + 3] = m.w;
    }
    if (tid < 32) sln[tid] = lnw[tid];

    const size_t base = (size_t)blockIdx.x * 64;
    {
        const float4* ysrc = (const float4*)(yws + base * 32);
        float4* ydst = (float4*)&sy[0][0];
        for (int i = tid; i < 512; i += 256) ydst[i] = ysrc[i];
    }
    __syncthreads();
    const float lnwc = sln[c];

#pragma unroll 1
    for (int p = 0; p < 8; ++p) {
        int r = p * 8 + rl;
        size_t row = base + r;
        float x1 = cd[row * 32 + c];
#pragma unroll
        for (int j4 = 0; j4 < 8; ++j4) {
            float4 yv = *(const float4*)&sy[r][j4 * 4];
            x1 += wa[j4 * 4 + 0] * yv.x + wa[j4 * 4 + 1] * yv.y +
                  wa[j4 * 4 + 2] * yv.z + wa[j4 * 4 + 3] * yv.w;
        }
        float s1 = x1, s2 = x1 * x1;
#pragma unroll
        for (int off = 16; off; off >>= 1) {
            s1 += __shfl_xor(s1, off);
            s2 += __shfl_xor(s2, off);
        }
        float mu = s1 * (1.0f / 32.0f);
        float var = s2 * (1.0f / 32.0f) - mu * mu;
        float hn = (x1 - mu) * rsqrtf(var + 1e-5f) * lnwc;
        shn[rl][c] = hn;
        float ga = 0.f;
#pragma unroll
        for (int j4 = 0; j4 < 8; ++j4) {
            float4 hv = *(const float4*)&shn[rl][j4 * 4];
            ga += wb[j4 * 4 + 0] * hv.x + wb[j4 * 4 + 1] * hv.y +
                  wb[j4 * 4 + 2] * hv.z + wb[j4 * 4 + 3] * hv.w;
        }
        float gv = gelu_exact(ga);
        sg[rl][c] = gv;
        float oa = x1;
#pragma unroll
        for (int j4 = 0; j4 < 8; ++j4) {
            float4 gvv = *(const float4*)&sg[rl][j4 * 4];
            oa += wm[j4 * 4 + 0] * gvv.x + wm[j4 * 4 + 1] * gvv.y +
                  wm[j4 * 4 + 2] * gvv.z + wm[j4 * 4 + 3] * gvv.w;
        }
        out[row * 32 + c] = oa;
    }
}

// ---------------------------------------------------------------------------
extern "C" void kernel_launch(void* const* d_in, const int* in_sizes, int n_in,
                              void* d_out, int out_size, void* d_ws, size_t ws_size,
                              hipStream_t stream) {
    const float* cd  = (const float*)d_in[0];
    const float* pkv = (const float*)d_in[1];
    const float* wqc = (const float*)d_in[2];
    const float* bqc = (const float*)d_in[3];
    const float* wqp = (const float*)d_in[4];
    const float* bqp = (const float*)d_in[5];
    const float* wkc = (const float*)d_in[6];
    const float* bkc = (const float*)d_in[7];
    const float* wkp = (const float*)d_in[8];
    const float* bkp = (const float*)d_in[9];
    const float* wvc = (const float*)d_in[10];
    const float* bvc = (const float*)d_in[11];
    const float* wvp = (const float*)d_in[12];
    const float* bvp = (const float*)d_in[13];
    const float* wcp = (const float*)d_in[14];
    const float* lnw = (const float*)d_in[15];
    const float* wfc = (const float*)d_in[16];
    const float* wmp = (const float*)d_in[17];

    // ws: qbf 2MB | kbf 0.5MB | vtbf 0.5MB | yws 4MB
    unsigned short* qbf  = (unsigned short*)d_ws;
    unsigned short* kbf  = qbf + (size_t)32 * 1024 * 32;
    unsigned short* vtbf = kbf + (size_t)8 * 1024 * 32;
    float* yws = (float*)(vtbf + (size_t)8 * 1024 * 32);

    tcl_merged<<<768, 256, 0, stream>>>(cd, pkv,
                                        wqc, bqc, wqp, bqp,
                                        wkc, bkc, wkp, bkp,
                                        wvc, bvc, wvp, bvp,
                                        qbf, kbf, vtbf);
    attn_kernel<<<1024, 256, 0, stream>>>(qbf, kbf, vtbf, yws);
    epi_kernel<<<512, 256, 0, stream>>>(cd, yws, wcp, lnw, wfc, wmp, (float*)d_out);
}

// Round 6
// 204.479 us; speedup vs baseline: 1.1916x; 1.1916x over previous
//
#include <hip/hip_runtime.h>

// B=8, F=4, T=S=1024, C=32, C2=64, NH=2, HD=16
// Inputs fp32, output fp32. q/k/v staged as bf16 for MFMA attention.
#define T_LEN 1024

typedef __attribute__((ext_vector_type(8))) short short8;   // 8 bf16 = 4 VGPR (MFMA A/B frag)
typedef __attribute__((ext_vector_type(4))) short short4v;
typedef __attribute__((ext_vector_type(4))) float float4v;  // MFMA C/D frag

__device__ __forceinline__ float gelu_exact(float x) {
    return 0.5f * x * (1.0f + erff(x * 0.70710678118654752440f));
}
__device__ __forceinline__ unsigned short f2bf(float f) {   // round-to-nearest-even
    unsigned u = __float_as_uint(f);
    u += 0x7fffu + ((u >> 16) & 1u);
    return (unsigned short)(u >> 16);
}

// ---------------------------------------------------------------------------
// Merged TCL for q/k/v: one dispatch, 768 blocks.
//   blocks [0,512)   : q from cd  -> qbf  row layout [32][1024][32]
//   blocks [512,640) : k from pkv -> kbf  row layout [8][1024][32]
//   blocks [640,768) : v from pkv -> vtbf transposed [8][2][16][1024]
// conv (causal k=3, 32->64): 4-row sliding window -> acc[4] only; live set
// wr[96]+acc[4]+6 row-frags ~ 125 VGPR (R5's acc[16] spilled at 256 cap).
// __launch_bounds__(256,3) caps allocator at 168 VGPR (3 waves/SIMD).
// proj (64->32): weight row in 64 regs via b128, activations via b128.
// ---------------------------------------------------------------------------
__global__ __launch_bounds__(256, 3) void tcl_merged(
    const float* __restrict__ cd, const float* __restrict__ pkv,
    const float* __restrict__ wqc, const float* __restrict__ bqc,
    const float* __restrict__ wqp, const float* __restrict__ bqp,
    const float* __restrict__ wkc, const float* __restrict__ bkc,
    const float* __restrict__ wkp, const float* __restrict__ bkp,
    const float* __restrict__ wvc, const float* __restrict__ bvc,
    const float* __restrict__ wvp, const float* __restrict__ bvp,
    unsigned short* __restrict__ qbf, unsigned short* __restrict__ kbf,
    unsigned short* __restrict__ vtbf)
{
    __shared__ float sx[70][32];     // x rows t0-2 .. t0+63 (+ slack)
    __shared__ float sh[64][68];     // conv+gelu out, pad 68 (16B-align, bank-safe)
    __shared__ float swp[32][68];    // proj weights [c][o] (row-major, padded)

    const int tid = threadIdx.x;
    const int gb = blockIdx.x;

    const float *src, *wc, *bc, *wp, *bp;
    unsigned short* outb;
    int n, mode;
    if (gb < 512)      { n = gb >> 4;          src = cd;  wc = wqc; bc = bqc; wp = wqp; bp = bqp; outb = qbf;  mode = 0; }
    else if (gb < 640) { n = (gb - 512) >> 4;  src = pkv; wc = wkc; bc = bkc; wp = wkp; bp = bkp; outb = kbf;  mode = 0; }
    else               { n = (gb - 640) >> 4;  src = pkv; wc = wvc; bc = bvc; wp = wvp; bp = bvp; outb = vtbf; mode = 1; }
    const int t0 = (gb & 15) * 64;

    // stage x tile (zero left pad); sx[r] = x[t0 - 2 + r]
    for (int i = tid; i < 66 * 32; i += 256) {
        int r = i >> 5, cc = i & 31;
        int t = t0 - 2 + r;
        sx[r][cc] = (t >= 0) ? src[((size_t)n * T_LEN + t) * 32 + cc] : 0.0f;
    }
    // stage proj weights row-major (coalesced)
    for (int i = tid; i < 2048; i += 256) {
        int cc = i >> 6, oo = i & 63;
        swp[cc][oo] = wp[i];
    }

    const int o = tid & 63;          // conv out channel
    const int tg = tid >> 6;         // wave id -> 16 consecutive t-rows
    float wr[96];                    // wr[c*3 + tap] for this lane's o
    {
        const float4* w4 = (const float4*)(wc + (size_t)o * 96);
#pragma unroll
        for (int i = 0; i < 24; ++i) {
            float4 u = w4[i];
            wr[i * 4 + 0] = u.x; wr[i * 4 + 1] = u.y;
            wr[i * 4 + 2] = u.z; wr[i * 4 + 3] = u.w;
        }
    }
    const float bco = bc[o];

    __syncthreads();

    // conv + gelu: y[tl][o] = b[o] + sum_c sum_tap w[o][c][tap]*sx[tl+tap][c]
    // 4 windows of 4 rows; per c-chunk read 6 row-fragments (broadcast b128).
    const int rbase = tg * 16;
#pragma unroll 1
    for (int win = 0; win < 4; ++win) {
        const int r0 = rbase + win * 4;
        float acc0 = bco, acc1 = bco, acc2 = bco, acc3 = bco;
#pragma unroll
        for (int c4 = 0; c4 < 8; ++c4) {
            const int bi = c4 * 12;
            float4 x0 = *(const float4*)&sx[r0 + 0][c4 * 4];
            float4 x1 = *(const float4*)&sx[r0 + 1][c4 * 4];
            float4 x2 = *(const float4*)&sx[r0 + 2][c4 * 4];
            float4 x3 = *(const float4*)&sx[r0 + 3][c4 * 4];
            float4 x4 = *(const float4*)&sx[r0 + 4][c4 * 4];
            float4 x5 = *(const float4*)&sx[r0 + 5][c4 * 4];
#define TAP0(v) (wr[bi + 0] * v.x + wr[bi + 3] * v.y + wr[bi + 6] * v.z + wr[bi + 9]  * v.w)
#define TAP1(v) (wr[bi + 1] * v.x + wr[bi + 4] * v.y + wr[bi + 7] * v.z + wr[bi + 10] * v.w)
#define TAP2(v) (wr[bi + 2] * v.x + wr[bi + 5] * v.y + wr[bi + 8] * v.z + wr[bi + 11] * v.w)
            acc0 += TAP0(x0) + TAP1(x1) + TAP2(x2);
            acc1 += TAP0(x1) + TAP1(x2) + TAP2(x3);
            acc2 += TAP0(x2) + TAP1(x3) + TAP2(x4);
            acc3 += TAP0(x3) + TAP1(x4) + TAP2(x5);
#undef TAP0
#undef TAP1
#undef TAP2
        }
        sh[r0 + 0][o] = gelu_exact(acc0);
        sh[r0 + 1][o] = gelu_exact(acc1);
        sh[r0 + 2][o] = gelu_exact(acc2);
        sh[r0 + 3][o] = gelu_exact(acc3);
    }

    __syncthreads();

    // proj: out[t][c] = bp[c] + sum_o h[t][o]*wp[c][o]
    int cc, rl;
    if (mode == 0) { cc = tid & 31; rl = tid >> 5; }
    else           { cc = tid >> 3; rl = tid & 7; }
    float wcol[64];
#pragma unroll
    for (int k4 = 0; k4 < 16; ++k4) {
        float4 wv = *(const float4*)&swp[cc][k4 * 4];
        wcol[k4 * 4 + 0] = wv.x; wcol[k4 * 4 + 1] = wv.y;
        wcol[k4 * 4 + 2] = wv.z; wcol[k4 * 4 + 3] = wv.w;
    }
    const float bpc = bp[cc];

#pragma unroll 1
    for (int it = 0; it < 8; ++it) {
        int tl = rl + it * 8;
        float a = bpc;
#pragma unroll
        for (int o4 = 0; o4 < 16; ++o4) {
            float4 hv = *(const float4*)&sh[tl][o4 * 4];
            a += wcol[o4 * 4 + 0] * hv.x + wcol[o4 * 4 + 1] * hv.y +
                 wcol[o4 * 4 + 2] * hv.z + wcol[o4 * 4 + 3] * hv.w;
        }
        if (mode == 0) {
            outb[((size_t)n * T_LEN + t0 + tl) * 32 + cc] = f2bf(a);
        } else {
            outb[((size_t)(n * 2 + (cc >> 4)) * 16 + (cc & 15)) * T_LEN + t0 + tl] = f2bf(a);
        }
    }
}

// ---------------------------------------------------------------------------
// MFMA attention. Block = 4 waves; wave = 16 q-rows; grid 64 bfh x 16 t-tiles.
// Per 32-s chunk: 2x QK mfma_f32_16x16x32_bf16 (d zero-padded 16->32),
// exp2 in C-frag, P -> per-wave LDS [t][s] (pitch 36 shorts), read back as
// A-frag (2x ds_read_b64), 1 dense PV MFMA accumulating y.
// Layouts (m89-verified): A[m=ln&15][k=quad*8+j], B[k=quad*8+j][n=ln&15],
// C[row=quad*4+i][col=ln&15].
// ---------------------------------------------------------------------------
__global__ __launch_bounds__(256) void attn_kernel(
    const unsigned short* __restrict__ qbf,   // [32][1024][32] bf16
    const unsigned short* __restrict__ kbf,   // [8][1024][32] bf16
    const unsigned short* __restrict__ vtbf,  // [8*2*16][1024] bf16 (V^T per head)
    float* __restrict__ yws)                  // [32][1024][32] f32
{
    __shared__ unsigned short plds[4 * 16 * 36];

    const int tid = threadIdx.x;
    const int w = tid >> 6;
    const int ln = tid & 63;
    const int sn = ln & 15;
    const int quad = ln >> 4;
    const int g = blockIdx.x;
    const int tt = g & 15;
    const int bfh = g >> 4;
    const int h = bfh & 1;
    const int bf = bfh >> 1;
    const int b = bf >> 2;
    const int trow = tt * 64 + w * 16 + sn;

    short8 aq = {0, 0, 0, 0, 0, 0, 0, 0};
    if (quad < 2)
        aq = *(const short8*)(qbf + ((size_t)bf * T_LEN + trow) * 32 + h * 16 + quad * 8);

    const unsigned short* kb = kbf + (size_t)b * T_LEN * 32 + h * 16 + quad * 8;
    const unsigned short* vb = vtbf + ((size_t)(b * 2 + h) * 16 + sn) * T_LEN + quad * 8;
    unsigned short* pw = plds + w * 576;

    float4v yacc = {0.f, 0.f, 0.f, 0.f};
    float l0 = 0.f, l1 = 0.f, l2 = 0.f, l3 = 0.f;
    const float SC = 0.36067376022224085f;    // 0.25 * log2(e)

#pragma unroll 1
    for (int s0 = 0; s0 < 1024; s0 += 32) {
        short8 bk0 = {0, 0, 0, 0, 0, 0, 0, 0};
        short8 bk1 = {0, 0, 0, 0, 0, 0, 0, 0};
        if (quad < 2) {
            bk0 = *(const short8*)(kb + (size_t)(s0 + sn) * 32);
            bk1 = *(const short8*)(kb + (size_t)(s0 + 16 + sn) * 32);
        }
        float4v z = {0.f, 0.f, 0.f, 0.f};
        float4v c0 = __builtin_amdgcn_mfma_f32_16x16x32_bf16(aq, bk0, z, 0, 0, 0);
        float4v c1 = __builtin_amdgcn_mfma_f32_16x16x32_bf16(aq, bk1, z, 0, 0, 0);

        float p00 = exp2f(c0.x * SC), p01 = exp2f(c0.y * SC);
        float p02 = exp2f(c0.z * SC), p03 = exp2f(c0.w * SC);
        float p10 = exp2f(c1.x * SC), p11 = exp2f(c1.y * SC);
        float p12 = exp2f(c1.z * SC), p13 = exp2f(c1.w * SC);
        l0 += p00 + p10; l1 += p01 + p11;
        l2 += p02 + p12; l3 += p03 + p13;

        const int tb = quad * 4;
        pw[(tb + 0) * 36 + sn]      = f2bf(p00);
        pw[(tb + 1) * 36 + sn]      = f2bf(p01);
        pw[(tb + 2) * 36 + sn]      = f2bf(p02);
        pw[(tb + 3) * 36 + sn]      = f2bf(p03);
        pw[(tb + 0) * 36 + 16 + sn] = f2bf(p10);
        pw[(tb + 1) * 36 + 16 + sn] = f2bf(p11);
        pw[(tb + 2) * 36 + 16 + sn] = f2bf(p12);
        pw[(tb + 3) * 36 + 16 + sn] = f2bf(p13);

        const unsigned short* pr = pw + sn * 36 + quad * 8;
        short4v plo = *(const short4v*)pr;
        short4v phi = *(const short4v*)(pr + 4);
        short8 ap = {plo.x, plo.y, plo.z, plo.w, phi.x, phi.y, phi.z, phi.w};

        short8 bv = *(const short8*)(vb + s0);
        yacc = __builtin_amdgcn_mfma_f32_16x16x32_bf16(ap, bv, yacc, 0, 0, 0);
    }

#pragma unroll
    for (int off = 1; off < 16; off <<= 1) {
        l0 += __shfl_xor(l0, off); l1 += __shfl_xor(l1, off);
        l2 += __shfl_xor(l2, off); l3 += __shfl_xor(l3, off);
    }
    const float i0 = 1.f / l0, i1 = 1.f / l1, i2 = 1.f / l2, i3 = 1.f / l3;

    float* yp = yws + ((size_t)bf * T_LEN + tt * 64 + w * 16 + quad * 4) * 32 + h * 16 + sn;
    yp[0 * 32] = yacc.x * i0;
    yp[1 * 32] = yacc.y * i1;
    yp[2 * 32] = yacc.z * i2;
    yp[3 * 32] = yacc.w * i3;
}

// ---------------------------------------------------------------------------
// Epilogue: out1 = cd + y@Wc^T; h = LN(out1)*ln_w; out = out1 + gelu(h@Wfc^T)@Wmp^T
// ---------------------------------------------------------------------------
__global__ __launch_bounds__(256) void epi_kernel(
    const float* __restrict__ cd, const float* __restrict__ yws,
    const float* __restrict__ wcp, const float* __restrict__ lnw,
    const float* __restrict__ wfc, const float* __restrict__ wmp,
    float* __restrict__ out)
{
    __shared__ float sy[64][32];
    __shared__ float shn[8][36], sg[8][36];
    __shared__ float sln[32];

    const int tid = threadIdx.x;
    const int rl = tid >> 5, c = tid & 31;

    float wa[32], wb[32], wm[32];
#pragma unroll
    for (int j4 = 0; j4 < 8; ++j4) {
        float4 a = *(const float4*)(wcp + c * 32 + j4 * 4);
        wa[j4 * 4 + 0] = a.x; wa[j4 * 4 + 1] = a.y; wa[j4 * 4 + 2] = a.z; wa[j4 * 4 + 3] = a.w;
        float4 f = *(const float4*)(wfc + c * 32 + j4 * 4);
        wb[j4 * 4 + 0] = f.x; wb[j4 * 4 + 1] = f.y; wb[j4 * 4 + 2] = f.z; wb[j4 * 4 + 3] = f.w;
        float4 m = *(const float4*)(wmp + c * 32 + j4 * 4);
        wm[j4 * 4 + 0] = m.x; wm[j4 * 4 + 1] = m.y; wm[j4 * 4 + 2] = m.z; wm[j4 * 4 + 3] = m.w;
    }
    if (tid < 32) sln[tid] = lnw[tid];

    const size_t base = (size_t)blockIdx.x * 64;
    {
        const float4* ysrc = (const float4*)(yws + base * 32);
        float4* ydst = (float4*)&sy[0][0];
        for (int i = tid; i < 512; i += 256) ydst[i] = ysrc[i];
    }
    __syncthreads();
    const float lnwc = sln[c];

#pragma unroll 1
    for (int p = 0; p < 8; ++p) {
        int r = p * 8 + rl;
        size_t row = base + r;
        float x1 = cd[row * 32 + c];
#pragma unroll
        for (int j4 = 0; j4 < 8; ++j4) {
            float4 yv = *(const float4*)&sy[r][j4 * 4];
            x1 += wa[j4 * 4 + 0] * yv.x + wa[j4 * 4 + 1] * yv.y +
                  wa[j4 * 4 + 2] * yv.z + wa[j4 * 4 + 3] * yv.w;
        }
        float s1 = x1, s2 = x1 * x1;
#pragma unroll
        for (int off = 16; off; off >>= 1) {
            s1 += __shfl_xor(s1, off);
            s2 += __shfl_xor(s2, off);
        }
        float mu = s1 * (1.0f / 32.0f);
        float var = s2 * (1.0f / 32.0f) - mu * mu;
        float hn = (x1 - mu) * rsqrtf(var + 1e-5f) * lnwc;
        shn[rl][c] = hn;
        float ga = 0.f;
#pragma unroll
        for (int j4 = 0; j4 < 8; ++j4) {
            float4 hv = *(const float4*)&shn[rl][j4 * 4];
            ga += wb[j4 * 4 + 0] * hv.x + wb[j4 * 4 + 1] * hv.y +
                  wb[j4 * 4 + 2] * hv.z + wb[j4 * 4 + 3] * hv.w;
        }
        float gv = gelu_exact(ga);
        sg[rl][c] = gv;
        float oa = x1;
#pragma unroll
        for (int j4 = 0; j4 < 8; ++j4) {
            float4 gvv = *(const float4*)&sg[rl][j4 * 4];
            oa += wm[j4 * 4 + 0] * gvv.x + wm[j4 * 4 + 1] * gvv.y +
                  wm[j4 * 4 + 2] * gvv.z + wm[j4 * 4 + 3] * gvv.w;
        }
        out[row * 32 + c] = oa;
    }
}

// ---------------------------------------------------------------------------
extern "C" void kernel_launch(void* const* d_in, const int* in_sizes, int n_in,
                              void* d_out, int out_size, void* d_ws, size_t ws_size,
                              hipStream_t stream) {
    const float* cd  = (const float*)d_in[0];
    const float* pkv = (const float*)d_in[1];
    const float* wqc = (const float*)d_in[2];
    const float* bqc = (const float*)d_in[3];
    const float* wqp = (const float*)d_in[4];
    const float* bqp = (const float*)d_in[5];
    const float* wkc = (const float*)d_in[6];
    const float* bkc = (const float*)d_in[7];
    const float* wkp = (const float*)d_in[8];
    const float* bkp = (const float*)d_in[9];
    const float* wvc = (const float*)d_in[10];
    const float* bvc = (const float*)d_in[11];
    const float* wvp = (const float*)d_in[12];
    const float* bvp = (const float*)d_in[13];
    const float* wcp = (const float*)d_in[14];
    const float* lnw = (const float*)d_in[15];
    const float* wfc = (const float*)d_in[16];
    const float* wmp = (const float*)d_in[17];

    // ws: qbf 2MB | kbf 0.5MB | vtbf 0.5MB | yws 4MB
    unsigned short* qbf  = (unsigned short*)d_ws;
    unsigned short* kbf  = qbf + (size_t)32 * 1024 * 32;
    unsigned short* vtbf = kbf + (size_t)8 * 1024 * 32;
    float* yws = (float*)(vtbf + (size_t)8 * 1024 * 32);

    tcl_merged<<<768, 256, 0, stream>>>(cd, pkv,
                                        wqc, bqc, wqp, bqp,
                                        wkc, bkc, wkp, bkp,
                                        wvc, bvc, wvp, bvp,
                                        qbf, kbf, vtbf);
    attn_kernel<<<1024, 256, 0, stream>>>(qbf, kbf, vtbf, yws);
    epi_kernel<<<512, 256, 0, stream>>>(cd, yws, wcp, lnw, wfc, wmp, (float*)d_out);
}

// Round 7
// 180.890 us; speedup vs baseline: 1.3470x; 1.1304x over previous
//
#include <hip/hip_runtime.h>

// B=8, F=4, T=S=1024, C=32, C2=64, NH=2, HD=16
// Inputs fp32, output fp32. q/k/v staged as bf16 for MFMA attention.
#define T_LEN 1024

typedef __attribute__((ext_vector_type(8))) short short8;   // 8 bf16 = 4 VGPR (MFMA A/B frag)
typedef __attribute__((ext_vector_type(4))) short short4v;
typedef __attribute__((ext_vector_type(4))) float float4v;  // MFMA C/D frag

__device__ __forceinline__ float gelu_exact(float x) {
    return 0.5f * x * (1.0f + erff(x * 0.70710678118654752440f));
}
__device__ __forceinline__ unsigned short f2bf(float f) {   // round-to-nearest-even
    unsigned u = __float_as_uint(f);
    u += 0x7fffu + ((u >> 16) & 1u);
    return (unsigned short)(u >> 16);
}

// ---------------------------------------------------------------------------
// Merged TCL for q/k/v: one dispatch, 768 blocks.
//   blocks [0,512)   : q from cd  -> qbf  row layout [32][1024][32]
//   blocks [512,640) : k from pkv -> kbf  row layout [8][1024][32]
//   blocks [640,768) : v from pkv -> vtbf transposed [8][2][16][1024]
// conv (causal k=3, 32->64): 4-row sliding window, weights lane-resident.
// NOTE: plain __launch_bounds__(256) — the (256,3) min-waves cap made the
// allocator demote wr[96]/wcol[64] to scratch (R6: VGPR=84, 212 MB HBM spill
// traffic). R4 proved this array pattern holds ~132 VGPR with no cap.
// ---------------------------------------------------------------------------
__global__ __launch_bounds__(256) void tcl_merged(
    const float* __restrict__ cd, const float* __restrict__ pkv,
    const float* __restrict__ wqc, const float* __restrict__ bqc,
    const float* __restrict__ wqp, const float* __restrict__ bqp,
    const float* __restrict__ wkc, const float* __restrict__ bkc,
    const float* __restrict__ wkp, const float* __restrict__ bkp,
    const float* __restrict__ wvc, const float* __restrict__ bvc,
    const float* __restrict__ wvp, const float* __restrict__ bvp,
    unsigned short* __restrict__ qbf, unsigned short* __restrict__ kbf,
    unsigned short* __restrict__ vtbf)
{
    __shared__ float sx[70][32];     // x rows t0-2 .. t0+63 (+ slack)
    __shared__ float sh[64][68];     // conv+gelu out, pad 68 (16B-align, bank-safe)
    __shared__ float swp[32][68];    // proj weights [c][o] (row-major, padded)

    const int tid = threadIdx.x;
    const int gb = blockIdx.x;

    const float *src, *wc, *bc, *wp, *bp;
    unsigned short* outb;
    int n, mode;
    if (gb < 512)      { n = gb >> 4;          src = cd;  wc = wqc; bc = bqc; wp = wqp; bp = bqp; outb = qbf;  mode = 0; }
    else if (gb < 640) { n = (gb - 512) >> 4;  src = pkv; wc = wkc; bc = bkc; wp = wkp; bp = bkp; outb = kbf;  mode = 0; }
    else               { n = (gb - 640) >> 4;  src = pkv; wc = wvc; bc = bvc; wp = wvp; bp = bvp; outb = vtbf; mode = 1; }
    const int t0 = (gb & 15) * 64;

    // stage x tile (zero left pad); sx[r] = x[t0 - 2 + r]
    for (int i = tid; i < 66 * 32; i += 256) {
        int r = i >> 5, cc = i & 31;
        int t = t0 - 2 + r;
        sx[r][cc] = (t >= 0) ? src[((size_t)n * T_LEN + t) * 32 + cc] : 0.0f;
    }
    // stage proj weights row-major (coalesced)
    for (int i = tid; i < 2048; i += 256) {
        int cc = i >> 6, oo = i & 63;
        swp[cc][oo] = wp[i];
    }

    const int o = tid & 63;          // conv out channel
    const int tg = tid >> 6;         // wave id -> 16 consecutive t-rows
    float wr[96];                    // wr[c*3 + tap] for this lane's o
    {
        const float4* w4 = (const float4*)(wc + (size_t)o * 96);
#pragma unroll
        for (int i = 0; i < 24; ++i) {
            float4 u = w4[i];
            wr[i * 4 + 0] = u.x; wr[i * 4 + 1] = u.y;
            wr[i * 4 + 2] = u.z; wr[i * 4 + 3] = u.w;
        }
    }
    const float bco = bc[o];

    __syncthreads();

    // conv + gelu: y[tl][o] = b[o] + sum_c sum_tap w[o][c][tap]*sx[tl+tap][c]
    // 4 windows of 4 rows; per c-chunk read 6 row-fragments (broadcast b128).
    const int rbase = tg * 16;
#pragma unroll 1
    for (int win = 0; win < 4; ++win) {
        const int r0 = rbase + win * 4;
        float acc0 = bco, acc1 = bco, acc2 = bco, acc3 = bco;
#pragma unroll
        for (int c4 = 0; c4 < 8; ++c4) {
            const int bi = c4 * 12;
            float4 x0 = *(const float4*)&sx[r0 + 0][c4 * 4];
            float4 x1 = *(const float4*)&sx[r0 + 1][c4 * 4];
            float4 x2 = *(const float4*)&sx[r0 + 2][c4 * 4];
            float4 x3 = *(const float4*)&sx[r0 + 3][c4 * 4];
            float4 x4 = *(const float4*)&sx[r0 + 4][c4 * 4];
            float4 x5 = *(const float4*)&sx[r0 + 5][c4 * 4];
#define TAP0(v) (wr[bi + 0] * v.x + wr[bi + 3] * v.y + wr[bi + 6] * v.z + wr[bi + 9]  * v.w)
#define TAP1(v) (wr[bi + 1] * v.x + wr[bi + 4] * v.y + wr[bi + 7] * v.z + wr[bi + 10] * v.w)
#define TAP2(v) (wr[bi + 2] * v.x + wr[bi + 5] * v.y + wr[bi + 8] * v.z + wr[bi + 11] * v.w)
            acc0 += TAP0(x0) + TAP1(x1) + TAP2(x2);
            acc1 += TAP0(x1) + TAP1(x2) + TAP2(x3);
            acc2 += TAP0(x2) + TAP1(x3) + TAP2(x4);
            acc3 += TAP0(x3) + TAP1(x4) + TAP2(x5);
#undef TAP0
#undef TAP1
#undef TAP2
        }
        sh[r0 + 0][o] = gelu_exact(acc0);
        sh[r0 + 1][o] = gelu_exact(acc1);
        sh[r0 + 2][o] = gelu_exact(acc2);
        sh[r0 + 3][o] = gelu_exact(acc3);
    }

    __syncthreads();

    // proj: out[t][c] = bp[c] + sum_o h[t][o]*wp[c][o]
    int cc, rl;
    if (mode == 0) { cc = tid & 31; rl = tid >> 5; }
    else           { cc = tid >> 3; rl = tid & 7; }
    float wcol[64];
#pragma unroll
    for (int k4 = 0; k4 < 16; ++k4) {
        float4 wv = *(const float4*)&swp[cc][k4 * 4];
        wcol[k4 * 4 + 0] = wv.x; wcol[k4 * 4 + 1] = wv.y;
        wcol[k4 * 4 + 2] = wv.z; wcol[k4 * 4 + 3] = wv.w;
    }
    const float bpc = bp[cc];

#pragma unroll 1
    for (int it = 0; it < 8; ++it) {
        int tl = rl + it * 8;
        float a = bpc;
#pragma unroll
        for (int o4 = 0; o4 < 16; ++o4) {
            float4 hv = *(const float4*)&sh[tl][o4 * 4];
            a += wcol[o4 * 4 + 0] * hv.x + wcol[o4 * 4 + 1] * hv.y +
                 wcol[o4 * 4 + 2] * hv.z + wcol[o4 * 4 + 3] * hv.w;
        }
        if (mode == 0) {
            outb[((size_t)n * T_LEN + t0 + tl) * 32 + cc] = f2bf(a);
        } else {
            outb[((size_t)(n * 2 + (cc >> 4)) * 16 + (cc & 15)) * T_LEN + t0 + tl] = f2bf(a);
        }
    }
}

// ---------------------------------------------------------------------------
// MFMA attention. Block = 4 waves; wave = 16 q-rows; grid 64 bfh x 16 t-tiles.
// Per 32-s chunk: 2x QK mfma_f32_16x16x32_bf16 (d zero-padded 16->32),
// exp2 in C-frag, P -> per-wave LDS [t][s] (pitch 36 shorts), read back as
// A-frag (2x ds_read_b64), 1 dense PV MFMA accumulating y.
// Layouts (m89-verified): A[m=ln&15][k=quad*8+j], B[k=quad*8+j][n=ln&15],
// C[row=quad*4+i][col=ln&15].
// ---------------------------------------------------------------------------
__global__ __launch_bounds__(256) void attn_kernel(
    const unsigned short* __restrict__ qbf,   // [32][1024][32] bf16
    const unsigned short* __restrict__ kbf,   // [8][1024][32] bf16
    const unsigned short* __restrict__ vtbf,  // [8*2*16][1024] bf16 (V^T per head)
    float* __restrict__ yws)                  // [32][1024][32] f32
{
    __shared__ unsigned short plds[4 * 16 * 36];

    const int tid = threadIdx.x;
    const int w = tid >> 6;
    const int ln = tid & 63;
    const int sn = ln & 15;
    const int quad = ln >> 4;
    const int g = blockIdx.x;
    const int tt = g & 15;
    const int bfh = g >> 4;
    const int h = bfh & 1;
    const int bf = bfh >> 1;
    const int b = bf >> 2;
    const int trow = tt * 64 + w * 16 + sn;

    short8 aq = {0, 0, 0, 0, 0, 0, 0, 0};
    if (quad < 2)
        aq = *(const short8*)(qbf + ((size_t)bf * T_LEN + trow) * 32 + h * 16 + quad * 8);

    const unsigned short* kb = kbf + (size_t)b * T_LEN * 32 + h * 16 + quad * 8;
    const unsigned short* vb = vtbf + ((size_t)(b * 2 + h) * 16 + sn) * T_LEN + quad * 8;
    unsigned short* pw = plds + w * 576;

    float4v yacc = {0.f, 0.f, 0.f, 0.f};
    float l0 = 0.f, l1 = 0.f, l2 = 0.f, l3 = 0.f;
    const float SC = 0.36067376022224085f;    // 0.25 * log2(e)

#pragma unroll 1
    for (int s0 = 0; s0 < 1024; s0 += 32) {
        short8 bk0 = {0, 0, 0, 0, 0, 0, 0, 0};
        short8 bk1 = {0, 0, 0, 0, 0, 0, 0, 0};
        if (quad < 2) {
            bk0 = *(const short8*)(kb + (size_t)(s0 + sn) * 32);
            bk1 = *(const short8*)(kb + (size_t)(s0 + 16 + sn) * 32);
        }
        float4v z = {0.f, 0.f, 0.f, 0.f};
        float4v c0 = __builtin_amdgcn_mfma_f32_16x16x32_bf16(aq, bk0, z, 0, 0, 0);
        float4v c1 = __builtin_amdgcn_mfma_f32_16x16x32_bf16(aq, bk1, z, 0, 0, 0);

        float p00 = exp2f(c0.x * SC), p01 = exp2f(c0.y * SC);
        float p02 = exp2f(c0.z * SC), p03 = exp2f(c0.w * SC);
        float p10 = exp2f(c1.x * SC), p11 = exp2f(c1.y * SC);
        float p12 = exp2f(c1.z * SC), p13 = exp2f(c1.w * SC);
        l0 += p00 + p10; l1 += p01 + p11;
        l2 += p02 + p12; l3 += p03 + p13;

        const int tb = quad * 4;
        pw[(tb + 0) * 36 + sn]      = f2bf(p00);
        pw[(tb + 1) * 36 + sn]      = f2bf(p01);
        pw[(tb + 2) * 36 + sn]      = f2bf(p02);
        pw[(tb + 3) * 36 + sn]      = f2bf(p03);
        pw[(tb + 0) * 36 + 16 + sn] = f2bf(p10);
        pw[(tb + 1) * 36 + 16 + sn] = f2bf(p11);
        pw[(tb + 2) * 36 + 16 + sn] = f2bf(p12);
        pw[(tb + 3) * 36 + 16 + sn] = f2bf(p13);

        const unsigned short* pr = pw + sn * 36 + quad * 8;
        short4v plo = *(const short4v*)pr;
        short4v phi = *(const short4v*)(pr + 4);
        short8 ap = {plo.x, plo.y, plo.z, plo.w, phi.x, phi.y, phi.z, phi.w};

        short8 bv = *(const short8*)(vb + s0);
        yacc = __builtin_amdgcn_mfma_f32_16x16x32_bf16(ap, bv, yacc, 0, 0, 0);
    }

#pragma unroll
    for (int off = 1; off < 16; off <<= 1) {
        l0 += __shfl_xor(l0, off); l1 += __shfl_xor(l1, off);
        l2 += __shfl_xor(l2, off); l3 += __shfl_xor(l3, off);
    }
    const float i0 = 1.f / l0, i1 = 1.f / l1, i2 = 1.f / l2, i3 = 1.f / l3;

    float* yp = yws + ((size_t)bf * T_LEN + tt * 64 + w * 16 + quad * 4) * 32 + h * 16 + sn;
    yp[0 * 32] = yacc.x * i0;
    yp[1 * 32] = yacc.y * i1;
    yp[2 * 32] = yacc.z * i2;
    yp[3 * 32] = yacc.w * i3;
}

// ---------------------------------------------------------------------------
// Epilogue: out1 = cd + y@Wc^T; h = LN(out1)*ln_w; out = out1 + gelu(h@Wfc^T)@Wmp^T
// ---------------------------------------------------------------------------
__global__ __launch_bounds__(256) void epi_kernel(
    const float* __restrict__ cd, const float* __restrict__ yws,
    const float* __restrict__ wcp, const float* __restrict__ lnw,
    const float* __restrict__ wfc, const float* __restrict__ wmp,
    float* __restrict__ out)
{
    __shared__ float sy[64][32];
    __shared__ float shn[8][36], sg[8][36];
    __shared__ float sln[32];

    const int tid = threadIdx.x;
    const int rl = tid >> 5, c = tid & 31;

    float wa[32], wb[32], wm[32];
#pragma unroll
    for (int j4 = 0; j4 < 8; ++j4) {
        float4 a = *(const float4*)(wcp + c * 32 + j4 * 4);
        wa[j4 * 4 + 0] = a.x; wa[j4 * 4 + 1] = a.y; wa[j4 * 4 + 2] = a.z; wa[j4 * 4 + 3] = a.w;
        float4 f = *(const float4*)(wfc + c * 32 + j4 * 4);
        wb[j4 * 4 + 0] = f.x; wb[j4 * 4 + 1] = f.y; wb[j4 * 4 + 2] = f.z; wb[j4 * 4 + 3] = f.w;
        float4 m = *(const float4*)(wmp + c * 32 + j4 * 4);
        wm[j4 * 4 + 0] = m.x; wm[j4 * 4 + 1] = m.y; wm[j4 * 4 + 2] = m.z; wm[j4 * 4 + 3] = m.w;
    }
    if (tid < 32) sln[tid] = lnw[tid];

    const size_t base = (size_t)blockIdx.x * 64;
    {
        const float4* ysrc = (const float4*)(yws + base * 32);
        float4* ydst = (float4*)&sy[0][0];
        for (int i = tid; i < 512; i += 256) ydst[i] = ysrc[i];
    }
    __syncthreads();
    const float lnwc = sln[c];

#pragma unroll 1
    for (int p = 0; p < 8; ++p) {
        int r = p * 8 + rl;
        size_t row = base + r;
        float x1 = cd[row * 32 + c];
#pragma unroll
        for (int j4 = 0; j4 < 8; ++j4) {
            float4 yv = *(const float4*)&sy[r][j4 * 4];
            x1 += wa[j4 * 4 + 0] * yv.x + wa[j4 * 4 + 1] * yv.y +
                  wa[j4 * 4 + 2] * yv.z + wa[j4 * 4 + 3] * yv.w;
        }
        float s1 = x1, s2 = x1 * x1;
#pragma unroll
        for (int off = 16; off; off >>= 1) {
            s1 += __shfl_xor(s1, off);
            s2 += __shfl_xor(s2, off);
        }
        float mu = s1 * (1.0f / 32.0f);
        float var = s2 * (1.0f / 32.0f) - mu * mu;
        float hn = (x1 - mu) * rsqrtf(var + 1e-5f) * lnwc;
        shn[rl][c] = hn;
        float ga = 0.f;
#pragma unroll
        for (int j4 = 0; j4 < 8; ++j4) {
            float4 hv = *(const float4*)&shn[rl][j4 * 4];
            ga += wb[j4 * 4 + 0] * hv.x + wb[j4 * 4 + 1] * hv.y +
                  wb[j4 * 4 + 2] * hv.z + wb[j4 * 4 + 3] * hv.w;
        }
        float gv = gelu_exact(ga);
        sg[rl][c] = gv;
        float oa = x1;
#pragma unroll
        for (int j4 = 0; j4 < 8; ++j4) {
            float4 gvv = *(const float4*)&sg[rl][j4 * 4];
            oa += wm[j4 * 4 + 0] * gvv.x + wm[j4 * 4 + 1] * gvv.y +
                  wm[j4 * 4 + 2] * gvv.z + wm[j4 * 4 + 3] * gvv.w;
        }
        out[row * 32 + c] = oa;
    }
}

// ---------------------------------------------------------------------------
extern "C" void kernel_launch(void* const* d_in, const int* in_sizes, int n_in,
                              void* d_out, int out_size, void* d_ws, size_t ws_size,
                              hipStream_t stream) {
    const float* cd  = (const float*)d_in[0];
    const float* pkv = (const float*)d_in[1];
    const float* wqc = (const float*)d_in[2];
    const float* bqc = (const float*)d_in[3];
    const float* wqp = (const float*)d_in[4];
    const float* bqp = (const float*)d_in[5];
    const float* wkc = (const float*)d_in[6];
    const float* bkc = (const float*)d_in[7];
    const float* wkp = (const float*)d_in[8];
    const float* bkp = (const float*)d_in[9];
    const float* wvc = (const float*)d_in[10];
    const float* bvc = (const float*)d_in[11];
    const float* wvp = (const float*)d_in[12];
    const float* bvp = (const float*)d_in[13];
    const float* wcp = (const float*)d_in[14];
    const float* lnw = (const float*)d_in[15];
    const float* wfc = (const float*)d_in[16];
    const float* wmp = (const float*)d_in[17];

    // ws: qbf 2MB | kbf 0.5MB | vtbf 0.5MB | yws 4MB
    unsigned short* qbf  = (unsigned short*)d_ws;
    unsigned short* kbf  = qbf + (size_t)32 * 1024 * 32;
    unsigned short* vtbf = kbf + (size_t)8 * 1024 * 32;
    float* yws = (float*)(vtbf + (size_t)8 * 1024 * 32);

    tcl_merged<<<768, 256, 0, stream>>>(cd, pkv,
                                        wqc, bqc, wqp, bqp,
                                        wkc, bkc, wkp, bkp,
                                        wvc, bvc, wvp, bvp,
                                        qbf, kbf, vtbf);
    attn_kernel<<<1024, 256, 0, stream>>>(qbf, kbf, vtbf, yws);
    epi_kernel<<<512, 256, 0, stream>>>(cd, yws, wcp, lnw, wfc, wmp, (float*)d_out);
}

// Round 8
// 145.606 us; speedup vs baseline: 1.6735x; 1.2423x over previous
//
#include <hip/hip_runtime.h>

// B=8, F=4, T=S=1024, C=32, C2=64, NH=2, HD=16
// Inputs fp32, output fp32. q/k/v staged as bf16 for MFMA attention.
#define T_LEN 1024

typedef __attribute__((ext_vector_type(8))) short short8;   // 8 bf16 = 4 VGPR (MFMA A/B frag)
typedef __attribute__((ext_vector_type(4))) short short4v;
typedef __attribute__((ext_vector_type(4))) float float4v;  // MFMA C/D frag

__device__ __forceinline__ float gelu_exact(float x) {
    return 0.5f * x * (1.0f + erff(x * 0.70710678118654752440f));
}
__device__ __forceinline__ unsigned short f2bf(float f) {   // round-to-nearest-even
    unsigned u = __float_as_uint(f);
    u += 0x7fffu + ((u >> 16) & 1u);
    return (unsigned short)(u >> 16);
}

// ---------------------------------------------------------------------------
// MFMA TCL for q/k/v: one dispatch, 768 blocks, 64 t-rows/block.
//   blocks [0,512)   : q from cd  -> qbf  [32][1024][32]
//   blocks [512,640) : k from pkv -> kbf  [8][1024][32]
//   blocks [640,768) : v from pkv -> vtbf [8][2][16][1024] (V^T)
// conv as im2col GEMM (tap-major k': A[t] = concat(x[t-2],x[t-1],x[t]),
// Wb'[tap*32+c][o] = wc[o][c][tap]): C64x64 = A[64x96]*Wb, 48 MFMAs/block.
// proj: [64x64]*[64x32], 16 MFMAs/block. Frag layouts = attn's (R4-verified).
// Pitches (shorts): A/WbT 96, Hb/WpB 72 -> conflict-free b128 frag reads.
// ---------------------------------------------------------------------------
__global__ __launch_bounds__(256) void tcl_mfma(
    const float* __restrict__ cd, const float* __restrict__ pkv,
    const float* __restrict__ wqc, const float* __restrict__ bqc,
    const float* __restrict__ wqp, const float* __restrict__ bqp,
    const float* __restrict__ wkc, const float* __restrict__ bkc,
    const float* __restrict__ wkp, const float* __restrict__ bkp,
    const float* __restrict__ wvc, const float* __restrict__ bvc,
    const float* __restrict__ wvp, const float* __restrict__ bvp,
    unsigned short* __restrict__ qbf, unsigned short* __restrict__ kbf,
    unsigned short* __restrict__ vtbf)
{
    __shared__ __align__(16) unsigned short Abuf[64 * 96];   // im2col A, bf16
    __shared__ __align__(16) unsigned short WbT[64 * 96];    // WbT[o][tap*32+c]
    __shared__ __align__(16) unsigned short Hb[64 * 72];     // gelu(conv) [t][o]
    __shared__ __align__(16) unsigned short WpB[32 * 72];    // wp [c][o]

    const int tid = threadIdx.x;
    const int gb = blockIdx.x;

    const float *src, *wc, *bc, *wp, *bp;
    unsigned short* outb;
    int n, mode;
    if (gb < 512)      { n = gb >> 4;          src = cd;  wc = wqc; bc = bqc; wp = wqp; bp = bqp; outb = qbf;  mode = 0; }
    else if (gb < 640) { n = (gb - 512) >> 4;  src = pkv; wc = wkc; bc = bkc; wp = wkp; bp = bkp; outb = kbf;  mode = 0; }
    else               { n = (gb - 640) >> 4;  src = pkv; wc = wvc; bc = bvc; wp = wvp; bp = bvp; outb = vtbf; mode = 1; }
    const int t0 = (gb & 15) * 64;

    // --- stage A (im2col, tap-major): A[t][tap*32 + c] = x[t0+t-2+tap][c]
    // 192 slices (t,tap) x 32 floats; 8 threads/slice; b64 bf16x4 stores.
#pragma unroll
    for (int it = 0; it < 6; ++it) {
        int s = (tid + it * 256) >> 3;        // 0..191
        int sub = tid & 7;
        int t = s / 3, tap = s - t * 3;
        int tau = t0 + t - 2 + tap;
        float4 xv = make_float4(0.f, 0.f, 0.f, 0.f);
        if (tau >= 0) xv = *(const float4*)&src[((size_t)n * T_LEN + tau) * 32 + sub * 4];
        short4v pk = { (short)f2bf(xv.x), (short)f2bf(xv.y),
                       (short)f2bf(xv.z), (short)f2bf(xv.w) };
        *(short4v*)&Abuf[t * 96 + tap * 32 + sub * 4] = pk;
    }
    // --- stage WbT[o][tap*32+c] = wc[o*96 + c*3 + tap]
#pragma unroll
    for (int it = 0; it < 6; ++it) {
        int i4 = tid + it * 256;              // float4 index, 0..1535
        int idx = i4 * 4;
        int o = idx / 96, r = idx - o * 96;   // r..r+3 same o (96 % 4 == 0)
        float4 w4 = *(const float4*)&wc[idx];
        float we[4] = { w4.x, w4.y, w4.z, w4.w };
#pragma unroll
        for (int e = 0; e < 4; ++e) {
            int re = r + e, c = re / 3, tap = re - c * 3;
            WbT[o * 96 + tap * 32 + c] = f2bf(we[e]);
        }
    }
    // --- stage WpB[c][o] = wp[c*64+o] (pitch 72)
#pragma unroll
    for (int it = 0; it < 2; ++it) {
        int i4 = tid + it * 256;              // 0..511
        int idx = i4 * 4;
        int c = idx >> 6, o = idx & 63;
        float4 w4 = *(const float4*)&wp[idx];
        short4v pk = { (short)f2bf(w4.x), (short)f2bf(w4.y),
                       (short)f2bf(w4.z), (short)f2bf(w4.w) };
        *(short4v*)&WpB[c * 72 + o] = pk;
    }

    const int w = tid >> 6;           // wave id: conv n-tile / proj m-tile
    const int ln = tid & 63;
    const int sn = ln & 15;
    const int quad = ln >> 4;

    const float bcv = bc[w * 16 + sn];        // conv bias for lane's col o
    const float bp0 = bp[sn], bp1 = bp[16 + sn];

    __syncthreads();

    // --- conv GEMM: C[t][o], wave w covers o-tile w, all 4 t-tiles
    short8 b0 = *(const short8*)&WbT[(w * 16 + sn) * 96 + 0  + quad * 8];
    short8 b1 = *(const short8*)&WbT[(w * 16 + sn) * 96 + 32 + quad * 8];
    short8 b2 = *(const short8*)&WbT[(w * 16 + sn) * 96 + 64 + quad * 8];
    float4v zero = { 0.f, 0.f, 0.f, 0.f };
    float4v acc[4] = { zero, zero, zero, zero };
#pragma unroll
    for (int tm = 0; tm < 4; ++tm) {
        const unsigned short* ar = &Abuf[(tm * 16 + sn) * 96 + quad * 8];
        short8 a0 = *(const short8*)(ar + 0);
        short8 a1 = *(const short8*)(ar + 32);
        short8 a2 = *(const short8*)(ar + 64);
        acc[tm] = __builtin_amdgcn_mfma_f32_16x16x32_bf16(a0, b0, acc[tm], 0, 0, 0);
        acc[tm] = __builtin_amdgcn_mfma_f32_16x16x32_bf16(a1, b1, acc[tm], 0, 0, 0);
        acc[tm] = __builtin_amdgcn_mfma_f32_16x16x32_bf16(a2, b2, acc[tm], 0, 0, 0);
    }
    // gelu + write Hb[t][o]
#pragma unroll
    for (int tm = 0; tm < 4; ++tm) {
        float ge[4];
        ge[0] = gelu_exact(acc[tm].x + bcv);
        ge[1] = gelu_exact(acc[tm].y + bcv);
        ge[2] = gelu_exact(acc[tm].z + bcv);
        ge[3] = gelu_exact(acc[tm].w + bcv);
#pragma unroll
        for (int i = 0; i < 4; ++i)
            Hb[(tm * 16 + quad * 4 + i) * 72 + w * 16 + sn] = f2bf(ge[i]);
    }

    __syncthreads();

    // --- proj GEMM: out[t][c], wave w = m-tile w, both c-tiles
    const unsigned short* hr = &Hb[(w * 16 + sn) * 72 + quad * 8];
    short8 pa0 = *(const short8*)(hr + 0);
    short8 pa1 = *(const short8*)(hr + 32);
    short8 pb00 = *(const short8*)&WpB[sn * 72 + quad * 8];
    short8 pb01 = *(const short8*)&WpB[sn * 72 + 32 + quad * 8];
    short8 pb10 = *(const short8*)&WpB[(16 + sn) * 72 + quad * 8];
    short8 pb11 = *(const short8*)&WpB[(16 + sn) * 72 + 32 + quad * 8];
    float4v acc0 = zero, acc1 = zero;
    acc0 = __builtin_amdgcn_mfma_f32_16x16x32_bf16(pa0, pb00, acc0, 0, 0, 0);
    acc0 = __builtin_amdgcn_mfma_f32_16x16x32_bf16(pa1, pb01, acc0, 0, 0, 0);
    acc1 = __builtin_amdgcn_mfma_f32_16x16x32_bf16(pa0, pb10, acc1, 0, 0, 0);
    acc1 = __builtin_amdgcn_mfma_f32_16x16x32_bf16(pa1, pb11, acc1, 0, 0, 0);

    float v0[4] = { acc0.x + bp0, acc0.y + bp0, acc0.z + bp0, acc0.w + bp0 };
    float v1[4] = { acc1.x + bp1, acc1.y + bp1, acc1.z + bp1, acc1.w + bp1 };
#pragma unroll
    for (int i = 0; i < 4; ++i) {
        int t = w * 16 + quad * 4 + i;
        if (mode == 0) {
            size_t rowb = ((size_t)n * T_LEN + t0 + t) * 32;
            outb[rowb + sn]      = f2bf(v0[i]);
            outb[rowb + 16 + sn] = f2bf(v1[i]);
        } else {
            // vtbf[((n*2 + h)*16 + d)*1024 + t], h = c>>4, d = c&15
            outb[((size_t)(n * 2 + 0) * 16 + sn) * T_LEN + t0 + t] = f2bf(v0[i]);
            outb[((size_t)(n * 2 + 1) * 16 + sn) * T_LEN + t0 + t] = f2bf(v1[i]);
        }
    }
}

// ---------------------------------------------------------------------------
// MFMA attention. Block = 4 waves; wave = 16 q-rows; grid 64 bfh x 16 t-tiles.
// Per 32-s chunk: 2x QK mfma_f32_16x16x32_bf16 (d zero-padded 16->32),
// exp2 in C-frag, P -> per-wave LDS [t][s] (pitch 36 shorts), read back as
// A-frag (2x ds_read_b64), 1 dense PV MFMA accumulating y.
// ---------------------------------------------------------------------------
__global__ __launch_bounds__(256) void attn_kernel(
    const unsigned short* __restrict__ qbf,   // [32][1024][32] bf16
    const unsigned short* __restrict__ kbf,   // [8][1024][32] bf16
    const unsigned short* __restrict__ vtbf,  // [8*2*16][1024] bf16 (V^T per head)
    float* __restrict__ yws)                  // [32][1024][32] f32
{
    __shared__ unsigned short plds[4 * 16 * 36];

    const int tid = threadIdx.x;
    const int w = tid >> 6;
    const int ln = tid & 63;
    const int sn = ln & 15;
    const int quad = ln >> 4;
    const int g = blockIdx.x;
    const int tt = g & 15;
    const int bfh = g >> 4;
    const int h = bfh & 1;
    const int bf = bfh >> 1;
    const int b = bf >> 2;
    const int trow = tt * 64 + w * 16 + sn;

    short8 aq = {0, 0, 0, 0, 0, 0, 0, 0};
    if (quad < 2)
        aq = *(const short8*)(qbf + ((size_t)bf * T_LEN + trow) * 32 + h * 16 + quad * 8);

    const unsigned short* kb = kbf + (size_t)b * T_LEN * 32 + h * 16 + quad * 8;
    const unsigned short* vb = vtbf + ((size_t)(b * 2 + h) * 16 + sn) * T_LEN + quad * 8;
    unsigned short* pw = plds + w * 576;

    float4v yacc = {0.f, 0.f, 0.f, 0.f};
    float l0 = 0.f, l1 = 0.f, l2 = 0.f, l3 = 0.f;
    const float SC = 0.36067376022224085f;    // 0.25 * log2(e)

#pragma unroll 1
    for (int s0 = 0; s0 < 1024; s0 += 32) {
        short8 bk0 = {0, 0, 0, 0, 0, 0, 0, 0};
        short8 bk1 = {0, 0, 0, 0, 0, 0, 0, 0};
        if (quad < 2) {
            bk0 = *(const short8*)(kb + (size_t)(s0 + sn) * 32);
            bk1 = *(const short8*)(kb + (size_t)(s0 + 16 + sn) * 32);
        }
        float4v z = {0.f, 0.f, 0.f, 0.f};
        float4v c0 = __builtin_amdgcn_mfma_f32_16x16x32_bf16(aq, bk0, z, 0, 0, 0);
        float4v c1 = __builtin_amdgcn_mfma_f32_16x16x32_bf16(aq, bk1, z, 0, 0, 0);

        float p00 = exp2f(c0.x * SC), p01 = exp2f(c0.y * SC);
        float p02 = exp2f(c0.z * SC), p03 = exp2f(c0.w * SC);
        float p10 = exp2f(c1.x * SC), p11 = exp2f(c1.y * SC);
        float p12 = exp2f(c1.z * SC), p13 = exp2f(c1.w * SC);
        l0 += p00 + p10; l1 += p01 + p11;
        l2 += p02 + p12; l3 += p03 + p13;

        const int tb = quad * 4;
        pw[(tb + 0) * 36 + sn]      = f2bf(p00);
        pw[(tb + 1) * 36 + sn]      = f2bf(p01);
        pw[(tb + 2) * 36 + sn]      = f2bf(p02);
        pw[(tb + 3) * 36 + sn]      = f2bf(p03);
        pw[(tb + 0) * 36 + 16 + sn] = f2bf(p10);
        pw[(tb + 1) * 36 + 16 + sn] = f2bf(p11);
        pw[(tb + 2) * 36 + 16 + sn] = f2bf(p12);
        pw[(tb + 3) * 36 + 16 + sn] = f2bf(p13);

        const unsigned short* pr = pw + sn * 36 + quad * 8;
        short4v plo = *(const short4v*)pr;
        short4v phi = *(const short4v*)(pr + 4);
        short8 ap = {plo.x, plo.y, plo.z, plo.w, phi.x, phi.y, phi.z, phi.w};

        short8 bv = *(const short8*)(vb + s0);
        yacc = __builtin_amdgcn_mfma_f32_16x16x32_bf16(ap, bv, yacc, 0, 0, 0);
    }

#pragma unroll
    for (int off = 1; off < 16; off <<= 1) {
        l0 += __shfl_xor(l0, off); l1 += __shfl_xor(l1, off);
        l2 += __shfl_xor(l2, off); l3 += __shfl_xor(l3, off);
    }
    const float i0 = 1.f / l0, i1 = 1.f / l1, i2 = 1.f / l2, i3 = 1.f / l3;

    float* yp = yws + ((size_t)bf * T_LEN + tt * 64 + w * 16 + quad * 4) * 32 + h * 16 + sn;
    yp[0 * 32] = yacc.x * i0;
    yp[1 * 32] = yacc.y * i1;
    yp[2 * 32] = yacc.z * i2;
    yp[3 * 32] = yacc.w * i3;
}

// ---------------------------------------------------------------------------
// Epilogue: out1 = cd + y@Wc^T; h = LN(out1)*ln_w; out = out1 + gelu(h@Wfc^T)@Wmp^T
// ---------------------------------------------------------------------------
__global__ __launch_bounds__(256) void epi_kernel(
    const float* __restrict__ cd, const float* __restrict__ yws,
    const float* __restrict__ wcp, const float* __restrict__ lnw,
    const float* __restrict__ wfc, const float* __restrict__ wmp,
    float* __restrict__ out)
{
    __shared__ float sy[64][32];
    __shared__ float shn[8][36], sg[8][36];
    __shared__ float sln[32];

    const int tid = threadIdx.x;
    const int rl = tid >> 5, c = tid & 31;

    float wa[32], wb[32], wm[32];
#pragma unroll
    for (int j4 = 0; j4 < 8; ++j4) {
        float4 a = *(const float4*)(wcp + c * 32 + j4 * 4);
        wa[j4 * 4 + 0] = a.x; wa[j4 * 4 + 1] = a.y; wa[j4 * 4 + 2] = a.z; wa[j4 * 4 + 3] = a.w;
        float4 f = *(const float4*)(wfc + c * 32 + j4 * 4);
        wb[j4 * 4 + 0] = f.x; wb[j4 * 4 + 1] = f.y; wb[j4 * 4 + 2] = f.z; wb[j4 * 4 + 3] = f.w;
        float4 m = *(const float4*)(wmp + c * 32 + j4 * 4);
        wm[j4 * 4 + 0] = m.x; wm[j4 * 4 + 1] = m.y; wm[j4 * 4 + 2] = m.z; wm[j4 * 4 + 3] = m.w;
    }
    if (tid < 32) sln[tid] = lnw[tid];

    const size_t base = (size_t)blockIdx.x * 64;
    {
        const float4* ysrc = (const float4*)(yws + base * 32);
        float4* ydst = (float4*)&sy[0][0];
        for (int i = tid; i < 512; i += 256) ydst[i] = ysrc[i];
    }
    __syncthreads();
    const float lnwc = sln[c];

#pragma unroll 1
    for (int p = 0; p < 8; ++p) {
        int r = p * 8 + rl;
        size_t row = base + r;
        float x1 = cd[row * 32 + c];
#pragma unroll
        for (int j4 = 0; j4 < 8; ++j4) {
            float4 yv = *(const float4*)&sy[r][j4 * 4];
            x1 += wa[j4 * 4 + 0] * yv.x + wa[j4 * 4 + 1] * yv.y +
                  wa[j4 * 4 + 2] * yv.z + wa[j4 * 4 + 3] * yv.w;
        }
        float s1 = x1, s2 = x1 * x1;
#pragma unroll
        for (int off = 16; off; off >>= 1) {
            s1 += __shfl_xor(s1, off);
            s2 += __shfl_xor(s2, off);
        }
        float mu = s1 * (1.0f / 32.0f);
        float var = s2 * (1.0f / 32.0f) - mu * mu;
        float hn = (x1 - mu) * rsqrtf(var + 1e-5f) * lnwc;
        shn[rl][c] = hn;
        float ga = 0.f;
#pragma unroll
        for (int j4 = 0; j4 < 8; ++j4) {
            float4 hv = *(const float4*)&shn[rl][j4 * 4];
            ga += wb[j4 * 4 + 0] * hv.x + wb[j4 * 4 + 1] * hv.y +
                  wb[j4 * 4 + 2] * hv.z + wb[j4 * 4 + 3] * hv.w;
        }
        float gv = gelu_exact(ga);
        sg[rl][c] = gv;
        float oa = x1;
#pragma unroll
        for (int j4 = 0; j4 < 8; ++j4) {
            float4 gvv = *(const float4*)&sg[rl][j4 * 4];
            oa += wm[j4 * 4 + 0] * gvv.x + wm[j4 * 4 + 1] * gvv.y +
                  wm[j4 * 4 + 2] * gvv.z + wm[j4 * 4 + 3] * gvv.w;
        }
        out[row * 32 + c] = oa;
    }
}

// ---------------------------------------------------------------------------
extern "C" void kernel_launch(void* const* d_in, const int* in_sizes, int n_in,
                              void* d_out, int out_size, void* d_ws, size_t ws_size,
                              hipStream_t stream) {
    const float* cd  = (const float*)d_in[0];
    const float* pkv = (const float*)d_in[1];
    const float* wqc = (const float*)d_in[2];
    const float* bqc = (const float*)d_in[3];
    const float* wqp = (const float*)d_in[4];
    const float* bqp = (const float*)d_in[5];
    const float* wkc = (const float*)d_in[6];
    const float* bkc = (const float*)d_in[7];
    const float* wkp = (const float*)d_in[8];
    const float* bkp = (const float*)d_in[9];
    const float* wvc = (const float*)d_in[10];
    const float* bvc = (const float*)d_in[11];
    const float* wvp = (const float*)d_in[12];
    const float* bvp = (const float*)d_in[13];
    const float* wcp = (const float*)d_in[14];
    const float* lnw = (const float*)d_in[15];
    const float* wfc = (const float*)d_in[16];
    const float* wmp = (const float*)d_in[17];

    // ws: qbf 2MB | kbf 0.5MB | vtbf 0.5MB | yws 4MB
    unsigned short* qbf  = (unsigned short*)d_ws;
    unsigned short* kbf  = qbf + (size_t)32 * 1024 * 32;
    unsigned short* vtbf = kbf + (size_t)8 * 1024 * 32;
    float* yws = (float*)(vtbf + (size_t)8 * 1024 * 32);

    tcl_mfma<<<768, 256, 0, stream>>>(cd, pkv,
                                      wqc, bqc, wqp, bqp,
                                      wkc, bkc, wkp, bkp,
                                      wvc, bvc, wvp, bvp,
                                      qbf, kbf, vtbf);
    attn_kernel<<<1024, 256, 0, stream>>>(qbf, kbf, vtbf, yws);
    epi_kernel<<<512, 256, 0, stream>>>(cd, yws, wcp, lnw, wfc, wmp, (float*)d_out);
}